// Round 4
// baseline (706.454 us; speedup 1.0000x reference)
//
#include <hip/hip_runtime.h>

#define EMBED 128

// ---------------- CSR build ----------------

__global__ void hist_kernel(const int* __restrict__ row, int* __restrict__ hist, int E4) {
    int i = blockIdx.x * blockDim.x + threadIdx.x;
    if (i < E4) {
        int4 r = ((const int4*)row)[i];
        atomicAdd(&hist[r.x], 1);
        atomicAdd(&hist[r.y], 1);
        atomicAdd(&hist[r.z], 1);
        atomicAdd(&hist[r.w], 1);
    }
}

// per-256-chunk exclusive scan; chunk totals -> bsums
__global__ void scan1(const int* __restrict__ hist, int* __restrict__ rs,
                      int* __restrict__ bsums, int N) {
    __shared__ int s[256];
    int i = blockIdx.x * 256 + threadIdx.x;
    int x = (i < N) ? hist[i] : 0;
    s[threadIdx.x] = x;
    __syncthreads();
    for (int off = 1; off < 256; off <<= 1) {
        int t = (threadIdx.x >= off) ? s[threadIdx.x - off] : 0;
        __syncthreads();
        s[threadIdx.x] += t;
        __syncthreads();
    }
    if (i < N) rs[i] = s[threadIdx.x] - x;        // exclusive, chunk-local
    if (threadIdx.x == 255) bsums[blockIdx.x] = s[255];
}

__global__ void scan2(int* __restrict__ bsums, int nb) {
    __shared__ int s[1024];
    __shared__ int carry;
    if (threadIdx.x == 0) carry = 0;
    __syncthreads();
    for (int base = 0; base < nb; base += 1024) {
        int i = base + threadIdx.x;
        int x = (i < nb) ? bsums[i] : 0;
        s[threadIdx.x] = x;
        __syncthreads();
        for (int off = 1; off < 1024; off <<= 1) {
            int t = (threadIdx.x >= off) ? s[threadIdx.x - off] : 0;
            __syncthreads();
            s[threadIdx.x] += t;
            __syncthreads();
        }
        if (i < nb) bsums[i] = s[threadIdx.x] - x + carry;
        __syncthreads();
        if (threadIdx.x == 0) carry += s[1023];
        __syncthreads();
    }
}

__global__ void scan3(int* __restrict__ rs, const int* __restrict__ bsums,
                      int* __restrict__ cursor, int N, int E) {
    int i = blockIdx.x * blockDim.x + threadIdx.x;
    if (i < N) {
        int v = rs[i] + bsums[i >> 8];
        rs[i] = v;
        cursor[i] = v;
    }
    if (i == 0) rs[N] = E;
}

// pack (col, val) into int2 -> one 8B random write, one 8B load later
__global__ void scatter_kernel(const int* __restrict__ row, const int* __restrict__ col,
                               const float* __restrict__ val, int* __restrict__ cursor,
                               int2* __restrict__ edges, int E4) {
    int i = blockIdx.x * blockDim.x + threadIdx.x;
    if (i < E4) {
        int4   r = ((const int4*)row)[i];
        int4   c = ((const int4*)col)[i];
        float4 v = ((const float4*)val)[i];
        int p0 = atomicAdd(&cursor[r.x], 1);
        edges[p0] = make_int2(c.x, __float_as_int(v.x));
        int p1 = atomicAdd(&cursor[r.y], 1);
        edges[p1] = make_int2(c.y, __float_as_int(v.y));
        int p2 = atomicAdd(&cursor[r.z], 1);
        edges[p2] = make_int2(c.z, __float_as_int(v.z));
        int p3 = atomicAdd(&cursor[r.w], 1);
        edges[p3] = make_int2(c.w, __float_as_int(v.w));
    }
}

// ---------------- SpMM: 2 rows per wave (32 lanes each), float4/lane ----------------
// Edge loop strip-mined into predicated chunks of 8: all loads issued before FMAs.

#define CHUNK 8

template <bool FIRST>
__global__ void spmm_kernel(const int* __restrict__ rs, const int2* __restrict__ edges,
                            const float* __restrict__ hin,
                            const float* __restrict__ uE, const float* __restrict__ iE,
                            float* __restrict__ hout, int N, int userNum) {
    int gid  = blockIdx.x * blockDim.x + threadIdx.x;
    int wave = gid >> 6;
    int lane = threadIdx.x & 63;
    int half = lane >> 5;
    int l32  = lane & 31;
    int row  = wave * 2 + half;
    if (row >= N) return;
    int s = rs[row], e = rs[row + 1];
    float4 acc = make_float4(0.f, 0.f, 0.f, 0.f);
    for (int k = s; k < e; k += CHUNK) {
        float4 x[CHUNK];
        float  v[CHUNK];
        #pragma unroll
        for (int j = 0; j < CHUNK; ++j) {
            bool ok  = (k + j) < e;
            int  idx = ok ? (k + j) : s;
            long long ed = __builtin_nontemporal_load((const long long*)&edges[idx]);
            int  c   = (int)(unsigned int)(ed & 0xffffffffLL);
            v[j]     = ok ? __int_as_float((int)(ed >> 32)) : 0.f;
            const float* src;
            if (FIRST) {
                src = (c < userNum) ? (uE + (size_t)c * EMBED)
                                    : (iE + (size_t)(c - userNum) * EMBED);
            } else {
                src = hin + (size_t)c * EMBED;
            }
            x[j] = *(const float4*)(src + 4 * l32);
        }
        #pragma unroll
        for (int j = 0; j < CHUNK; ++j) {
            acc.x += v[j] * x[j].x;
            acc.y += v[j] * x[j].y;
            acc.z += v[j] * x[j].z;
            acc.w += v[j] * x[j].w;
        }
    }
    float4* outp = (float4*)(hout + (size_t)row * EMBED + 4 * l32);
    __builtin_nontemporal_store(acc.x, &outp->x);
    __builtin_nontemporal_store(acc.y, &outp->y);
    __builtin_nontemporal_store(acc.z, &outp->z);
    __builtin_nontemporal_store(acc.w, &outp->w);
}

// layer-3 SpMM restricted to the 2B sampled rows; accumulates into accU/accV
__global__ void spmm_sel_kernel(const int* __restrict__ rs, const int2* __restrict__ edges,
                                const float* __restrict__ hin,
                                const int* __restrict__ uIdx, const int* __restrict__ vIdx,
                                float* __restrict__ accU, float* __restrict__ accV,
                                int B, int userNum) {
    int gid  = blockIdx.x * blockDim.x + threadIdx.x;
    int wave = gid >> 6;
    int lane = threadIdx.x & 63;
    int half = lane >> 5;
    int l32  = lane & 31;
    int b    = wave * 2 + half;
    if (b >= 2 * B) return;
    int row;
    float* dst;
    if (b < B) {
        row = uIdx[b];
        dst = accU + (size_t)b * EMBED;
    } else {
        row = userNum + vIdx[b - B];
        dst = accV + (size_t)(b - B) * EMBED;
    }
    int s = rs[row], e = rs[row + 1];
    float4 acc = make_float4(0.f, 0.f, 0.f, 0.f);
    for (int k = s; k < e; k += CHUNK) {
        float4 x[CHUNK];
        float  v[CHUNK];
        #pragma unroll
        for (int j = 0; j < CHUNK; ++j) {
            bool ok  = (k + j) < e;
            int  idx = ok ? (k + j) : s;
            long long ed = __builtin_nontemporal_load((const long long*)&edges[idx]);
            int  c   = (int)(unsigned int)(ed & 0xffffffffLL);
            v[j]     = ok ? __int_as_float((int)(ed >> 32)) : 0.f;
            x[j]     = *(const float4*)(hin + (size_t)c * EMBED + 4 * l32);
        }
        #pragma unroll
        for (int j = 0; j < CHUNK; ++j) {
            acc.x += v[j] * x[j].x;
            acc.y += v[j] * x[j].y;
            acc.z += v[j] * x[j].z;
            acc.w += v[j] * x[j].w;
        }
    }
    float4* dp = (float4*)(dst + 4 * l32);
    float4 d = *dp;
    d.x += acc.x; d.y += acc.y; d.z += acc.z; d.w += acc.w;
    *dp = d;
}

// acc(layers 0..2) = emb + h1 + h2 at the sampled rows, single write
__global__ void gather_fused(const float* __restrict__ uE, const float* __restrict__ iE,
                             const float* __restrict__ h1, const float* __restrict__ h2,
                             const int* __restrict__ uIdx, const int* __restrict__ vIdx,
                             float* __restrict__ accU, float* __restrict__ accV,
                             int B, int userNum) {
    int gid  = blockIdx.x * blockDim.x + threadIdx.x;
    int wave = gid >> 6;
    int lane = threadIdx.x & 63;
    int half = lane >> 5;
    int l32  = lane & 31;
    int b    = wave * 2 + half;
    if (b >= 2 * B) return;
    const float* emb;
    size_t ro;
    float* dst;
    if (b < B) {
        int u = uIdx[b];
        emb = uE + (size_t)u * EMBED;
        ro  = (size_t)u * EMBED;
        dst = accU + (size_t)b * EMBED;
    } else {
        int it = vIdx[b - B];
        emb = iE + (size_t)it * EMBED;
        ro  = (size_t)(userNum + it) * EMBED;
        dst = accV + (size_t)(b - B) * EMBED;
    }
    float4 a  = *(const float4*)(emb + 4 * l32);
    float4 x1 = *(const float4*)(h1 + ro + 4 * l32);
    float4 x2 = *(const float4*)(h2 + ro + 4 * l32);
    a.x += x1.x + x2.x;
    a.y += x1.y + x2.y;
    a.z += x1.z + x2.z;
    a.w += x1.w + x2.w;
    *(float4*)(dst + 4 * l32) = a;
}

__global__ void dot_kernel(const float* __restrict__ accU, const float* __restrict__ accV,
                           float* __restrict__ out, int B) {
    int gid  = blockIdx.x * blockDim.x + threadIdx.x;
    int wave = gid >> 6;
    int lane = threadIdx.x & 63;
    int half = lane >> 5;
    int l32  = lane & 31;
    int b    = wave * 2 + half;
    if (b >= B) return;
    float4 a = *(const float4*)(accU + (size_t)b * EMBED + 4 * l32);
    float4 v = *(const float4*)(accV + (size_t)b * EMBED + 4 * l32);
    float s = a.x * v.x + a.y * v.y + a.z * v.z + a.w * v.w;
    #pragma unroll
    for (int off = 16; off > 0; off >>= 1) s += __shfl_down(s, off, 32);
    if (l32 == 0) out[b] = s * (1.f / 16.f);   // (acc/4)·(acc/4)
}

// ---------------- launch ----------------

extern "C" void kernel_launch(void* const* d_in, const int* in_sizes, int n_in,
                              void* d_out, int out_size, void* d_ws, size_t ws_size,
                              hipStream_t stream) {
    const float* uE      = (const float*)d_in[0];
    const float* iE      = (const float*)d_in[1];
    const float* L_val   = (const float*)d_in[2];
    const int*   L_row   = (const int*)d_in[3];
    const int*   L_col   = (const int*)d_in[4];
    const int*   userIdx = (const int*)d_in[5];
    const int*   itemIdx = (const int*)d_in[6];

    const int userNum = in_sizes[0] / EMBED;   // 100000
    const int itemNum = in_sizes[1] / EMBED;   // 50000
    const int N = userNum + itemNum;           // 150000
    const int E = in_sizes[2];                 // 2000000 (multiple of 4)
    const int B = in_sizes[5];                 // 16384
    float* out = (float*)d_out;

    char* ws = (char*)d_ws;
    size_t off = 0;
    auto alloc = [&](size_t bytes) -> void* {
        void* p = ws + off;
        off += (bytes + 1023) & ~(size_t)1023;
        return p;
    };
    float* h_a    = (float*)alloc((size_t)N * EMBED * 4);
    float* h_b    = (float*)alloc((size_t)N * EMBED * 4);
    int2*  edges  = (int2*) alloc((size_t)E * 8);
    int*   rs     = (int*)  alloc((size_t)(N + 1) * 4);
    int*   cursor = (int*)  alloc((size_t)N * 4);
    int*   hist   = (int*)  alloc((size_t)N * 4);
    int*   bsums  = (int*)  alloc(8192);
    float* accU   = (float*)alloc((size_t)B * EMBED * 4);
    float* accV   = (float*)alloc((size_t)B * EMBED * 4);
    (void)off; (void)ws_size; (void)n_in; (void)out_size;

    const int tb = 256;

    // CSR build (E is a multiple of 4: 2 * 1e6)
    (void)hipMemsetAsync(hist, 0, (size_t)N * 4, stream);
    const int E4 = E / 4;
    hist_kernel<<<(E4 + tb - 1) / tb, tb, 0, stream>>>(L_row, hist, E4);
    const int nb = (N + 255) / 256;
    scan1<<<nb, 256, 0, stream>>>(hist, rs, bsums, N);
    scan2<<<1, 1024, 0, stream>>>(bsums, nb);
    scan3<<<(N + tb - 1) / tb, tb, 0, stream>>>(rs, bsums, cursor, N, E);
    scatter_kernel<<<(E4 + tb - 1) / tb, tb, 0, stream>>>(L_row, L_col, L_val, cursor,
                                                          edges, E4);

    // propagation
    const int spmm_blocks = (N + 7) / 8;        // 8 rows per 256-thread block
    spmm_kernel<true ><<<spmm_blocks, 256, 0, stream>>>(rs, edges, nullptr, uE, iE, h_a, N, userNum);
    spmm_kernel<false><<<spmm_blocks, 256, 0, stream>>>(rs, edges, h_a, uE, iE, h_b, N, userNum);

    const int gb = (2 * B + 7) / 8;
    gather_fused<<<gb, 256, 0, stream>>>(uE, iE, h_a, h_b, userIdx, itemIdx,
                                         accU, accV, B, userNum);
    spmm_sel_kernel<<<gb, 256, 0, stream>>>(rs, edges, h_b, userIdx, itemIdx,
                                            accU, accV, B, userNum);

    dot_kernel<<<(B + 7) / 8, 256, 0, stream>>>(accU, accV, out, B);
}

// Round 5
// 600.068 us; speedup vs baseline: 1.1773x; 1.1773x over previous
//
#include <hip/hip_runtime.h>
#include <hip/hip_fp16.h>

#define EMBED 128
#define CHUNK 8

// ---------------- CSR build ----------------

__global__ void hist_kernel(const int* __restrict__ row, int* __restrict__ hist, int E4) {
    int i = blockIdx.x * blockDim.x + threadIdx.x;
    if (i < E4) {
        int4 r = ((const int4*)row)[i];
        atomicAdd(&hist[r.x], 1);
        atomicAdd(&hist[r.y], 1);
        atomicAdd(&hist[r.z], 1);
        atomicAdd(&hist[r.w], 1);
    }
}

__global__ void scan1(const int* __restrict__ hist, int* __restrict__ rs,
                      int* __restrict__ bsums, int N) {
    __shared__ int s[256];
    int i = blockIdx.x * 256 + threadIdx.x;
    int x = (i < N) ? hist[i] : 0;
    s[threadIdx.x] = x;
    __syncthreads();
    for (int off = 1; off < 256; off <<= 1) {
        int t = (threadIdx.x >= off) ? s[threadIdx.x - off] : 0;
        __syncthreads();
        s[threadIdx.x] += t;
        __syncthreads();
    }
    if (i < N) rs[i] = s[threadIdx.x] - x;
    if (threadIdx.x == 255) bsums[blockIdx.x] = s[255];
}

__global__ void scan2(int* __restrict__ bsums, int nb) {
    __shared__ int s[1024];
    __shared__ int carry;
    if (threadIdx.x == 0) carry = 0;
    __syncthreads();
    for (int base = 0; base < nb; base += 1024) {
        int i = base + threadIdx.x;
        int x = (i < nb) ? bsums[i] : 0;
        s[threadIdx.x] = x;
        __syncthreads();
        for (int off = 1; off < 1024; off <<= 1) {
            int t = (threadIdx.x >= off) ? s[threadIdx.x - off] : 0;
            __syncthreads();
            s[threadIdx.x] += t;
            __syncthreads();
        }
        if (i < nb) bsums[i] = s[threadIdx.x] - x + carry;
        __syncthreads();
        if (threadIdx.x == 0) carry += s[1023];
        __syncthreads();
    }
}

__global__ void scan3(int* __restrict__ rs, const int* __restrict__ bsums,
                      int* __restrict__ cursor, int N, int E) {
    int i = blockIdx.x * blockDim.x + threadIdx.x;
    if (i < N) {
        int v = rs[i] + bsums[i >> 8];
        rs[i] = v;
        cursor[i] = v;
    }
    if (i == 0) rs[N] = E;
}

__global__ void scatter_kernel(const int* __restrict__ row, const int* __restrict__ col,
                               const float* __restrict__ val, int* __restrict__ cursor,
                               int2* __restrict__ edges, int E4) {
    int i = blockIdx.x * blockDim.x + threadIdx.x;
    if (i < E4) {
        int4   r = ((const int4*)row)[i];
        int4   c = ((const int4*)col)[i];
        float4 v = ((const float4*)val)[i];
        int p0 = atomicAdd(&cursor[r.x], 1);
        edges[p0] = make_int2(c.x, __float_as_int(v.x));
        int p1 = atomicAdd(&cursor[r.y], 1);
        edges[p1] = make_int2(c.y, __float_as_int(v.y));
        int p2 = atomicAdd(&cursor[r.z], 1);
        edges[p2] = make_int2(c.z, __float_as_int(v.z));
        int p3 = atomicAdd(&cursor[r.w], 1);
        edges[p3] = make_int2(c.w, __float_as_int(v.w));
    }
}

// ---------------- fp32 -> fp16 convert (8 elems/thread) ----------------

__global__ void f32_to_f16(const float* __restrict__ src, __half* __restrict__ dst, int n8) {
    int i = blockIdx.x * blockDim.x + threadIdx.x;
    if (i >= n8) return;
    float4 a = ((const float4*)src)[2 * i];
    float4 b = ((const float4*)src)[2 * i + 1];
    __half2 h0 = __floats2half2_rn(a.x, a.y);
    __half2 h1 = __floats2half2_rn(a.z, a.w);
    __half2 h2 = __floats2half2_rn(b.x, b.y);
    __half2 h3 = __floats2half2_rn(b.z, b.w);
    uint4 o;
    o.x = *(unsigned int*)&h0;
    o.y = *(unsigned int*)&h1;
    o.z = *(unsigned int*)&h2;
    o.w = *(unsigned int*)&h3;
    ((uint4*)dst)[i] = o;
}

// ---------------- SpMM: 2 rows/wave (32 lanes each), fp16 h, fp32 acc ----------------
// lane l32 owns elements [4*l32, 4*l32+4) of the row; gather = 8 B/lane/edge.

__global__ void spmm_kernel(const int* __restrict__ rs, const int2* __restrict__ edges,
                            const __half* __restrict__ hin, __half* __restrict__ hout,
                            int N) {
    int gid  = blockIdx.x * blockDim.x + threadIdx.x;
    int wave = gid >> 6;
    int lane = threadIdx.x & 63;
    int half = lane >> 5;
    int l32  = lane & 31;
    int row  = wave * 2 + half;
    if (row >= N) return;
    int s = rs[row], e = rs[row + 1];
    float4 acc = make_float4(0.f, 0.f, 0.f, 0.f);
    for (int k = s; k < e; k += CHUNK) {
        uint2 raw[CHUNK];
        float vv[CHUNK];
        #pragma unroll
        for (int j = 0; j < CHUNK; ++j) {
            bool ok  = (k + j) < e;
            int  idx = ok ? (k + j) : s;
            int2 ed  = edges[idx];
            vv[j]    = ok ? __int_as_float(ed.y) : 0.f;
            raw[j]   = *(const uint2*)(hin + (size_t)ed.x * EMBED + 4 * l32);
        }
        #pragma unroll
        for (int j = 0; j < CHUNK; ++j) {
            float2 f0 = __half22float2(*(__half2*)&raw[j].x);
            float2 f1 = __half22float2(*(__half2*)&raw[j].y);
            acc.x += vv[j] * f0.x;
            acc.y += vv[j] * f0.y;
            acc.z += vv[j] * f1.x;
            acc.w += vv[j] * f1.y;
        }
    }
    __half2 o0 = __floats2half2_rn(acc.x, acc.y);
    __half2 o1 = __floats2half2_rn(acc.z, acc.w);
    uint2 o;
    o.x = *(unsigned int*)&o0;
    o.y = *(unsigned int*)&o1;
    *(uint2*)(hout + (size_t)row * EMBED + 4 * l32) = o;
}

// layer-3 SpMM restricted to the 2B sampled rows; accumulates fp32 into accU/accV
__global__ void spmm_sel_kernel(const int* __restrict__ rs, const int2* __restrict__ edges,
                                const __half* __restrict__ hin,
                                const int* __restrict__ uIdx, const int* __restrict__ vIdx,
                                float* __restrict__ accU, float* __restrict__ accV,
                                int B, int userNum) {
    int gid  = blockIdx.x * blockDim.x + threadIdx.x;
    int wave = gid >> 6;
    int lane = threadIdx.x & 63;
    int half = lane >> 5;
    int l32  = lane & 31;
    int b    = wave * 2 + half;
    if (b >= 2 * B) return;
    int row;
    float* dst;
    if (b < B) {
        row = uIdx[b];
        dst = accU + (size_t)b * EMBED;
    } else {
        row = userNum + vIdx[b - B];
        dst = accV + (size_t)(b - B) * EMBED;
    }
    int s = rs[row], e = rs[row + 1];
    float4 acc = make_float4(0.f, 0.f, 0.f, 0.f);
    for (int k = s; k < e; k += CHUNK) {
        uint2 raw[CHUNK];
        float vv[CHUNK];
        #pragma unroll
        for (int j = 0; j < CHUNK; ++j) {
            bool ok  = (k + j) < e;
            int  idx = ok ? (k + j) : s;
            int2 ed  = edges[idx];
            vv[j]    = ok ? __int_as_float(ed.y) : 0.f;
            raw[j]   = *(const uint2*)(hin + (size_t)ed.x * EMBED + 4 * l32);
        }
        #pragma unroll
        for (int j = 0; j < CHUNK; ++j) {
            float2 f0 = __half22float2(*(__half2*)&raw[j].x);
            float2 f1 = __half22float2(*(__half2*)&raw[j].y);
            acc.x += vv[j] * f0.x;
            acc.y += vv[j] * f0.y;
            acc.z += vv[j] * f1.x;
            acc.w += vv[j] * f1.y;
        }
    }
    float4* dp = (float4*)(dst + 4 * l32);
    float4 d = *dp;
    d.x += acc.x; d.y += acc.y; d.z += acc.z; d.w += acc.w;
    *dp = d;
}

// acc(layers 0..2) = emb(fp32) + h1(fp16) + h2(fp16) at sampled rows
__global__ void gather_fused(const float* __restrict__ uE, const float* __restrict__ iE,
                             const __half* __restrict__ h1, const __half* __restrict__ h2,
                             const int* __restrict__ uIdx, const int* __restrict__ vIdx,
                             float* __restrict__ accU, float* __restrict__ accV,
                             int B, int userNum) {
    int gid  = blockIdx.x * blockDim.x + threadIdx.x;
    int wave = gid >> 6;
    int lane = threadIdx.x & 63;
    int half = lane >> 5;
    int l32  = lane & 31;
    int b    = wave * 2 + half;
    if (b >= 2 * B) return;
    const float* emb;
    size_t ro;
    float* dst;
    if (b < B) {
        int u = uIdx[b];
        emb = uE + (size_t)u * EMBED;
        ro  = (size_t)u * EMBED;
        dst = accU + (size_t)b * EMBED;
    } else {
        int it = vIdx[b - B];
        emb = iE + (size_t)it * EMBED;
        ro  = (size_t)(userNum + it) * EMBED;
        dst = accV + (size_t)(b - B) * EMBED;
    }
    float4 a = *(const float4*)(emb + 4 * l32);
    uint2 r1 = *(const uint2*)(h1 + ro + 4 * l32);
    uint2 r2 = *(const uint2*)(h2 + ro + 4 * l32);
    float2 x0 = __half22float2(*(__half2*)&r1.x);
    float2 x1 = __half22float2(*(__half2*)&r1.y);
    float2 y0 = __half22float2(*(__half2*)&r2.x);
    float2 y1 = __half22float2(*(__half2*)&r2.y);
    a.x += x0.x + y0.x;
    a.y += x0.y + y0.y;
    a.z += x1.x + y1.x;
    a.w += x1.y + y1.y;
    *(float4*)(dst + 4 * l32) = a;
}

__global__ void dot_kernel(const float* __restrict__ accU, const float* __restrict__ accV,
                           float* __restrict__ out, int B) {
    int gid  = blockIdx.x * blockDim.x + threadIdx.x;
    int wave = gid >> 6;
    int lane = threadIdx.x & 63;
    int half = lane >> 5;
    int l32  = lane & 31;
    int b    = wave * 2 + half;
    if (b >= B) return;
    float4 a = *(const float4*)(accU + (size_t)b * EMBED + 4 * l32);
    float4 v = *(const float4*)(accV + (size_t)b * EMBED + 4 * l32);
    float s = a.x * v.x + a.y * v.y + a.z * v.z + a.w * v.w;
    #pragma unroll
    for (int off = 16; off > 0; off >>= 1) s += __shfl_down(s, off, 32);
    if (l32 == 0) out[b] = s * (1.f / 16.f);   // (acc/4)·(acc/4)
}

// ---------------- launch ----------------

extern "C" void kernel_launch(void* const* d_in, const int* in_sizes, int n_in,
                              void* d_out, int out_size, void* d_ws, size_t ws_size,
                              hipStream_t stream) {
    const float* uE      = (const float*)d_in[0];
    const float* iE      = (const float*)d_in[1];
    const float* L_val   = (const float*)d_in[2];
    const int*   L_row   = (const int*)d_in[3];
    const int*   L_col   = (const int*)d_in[4];
    const int*   userIdx = (const int*)d_in[5];
    const int*   itemIdx = (const int*)d_in[6];

    const int userNum = in_sizes[0] / EMBED;   // 100000
    const int itemNum = in_sizes[1] / EMBED;   // 50000
    const int N = userNum + itemNum;           // 150000
    const int E = in_sizes[2];                 // 2000000 (multiple of 4)
    const int B = in_sizes[5];                 // 16384
    float* out = (float*)d_out;

    char* ws = (char*)d_ws;
    size_t off = 0;
    auto alloc = [&](size_t bytes) -> void* {
        void* p = ws + off;
        off += (bytes + 1023) & ~(size_t)1023;
        return p;
    };
    __half* h0   = (__half*)alloc((size_t)N * EMBED * 2);
    __half* h1   = (__half*)alloc((size_t)N * EMBED * 2);
    __half* h2   = (__half*)alloc((size_t)N * EMBED * 2);
    int2*  edges  = (int2*) alloc((size_t)E * 8);
    int*   rs     = (int*)  alloc((size_t)(N + 1) * 4);
    int*   cursor = (int*)  alloc((size_t)N * 4);
    int*   hist   = (int*)  alloc((size_t)N * 4);
    int*   bsums  = (int*)  alloc(8192);
    float* accU   = (float*)alloc((size_t)B * EMBED * 4);
    float* accV   = (float*)alloc((size_t)B * EMBED * 4);
    (void)off; (void)ws_size; (void)n_in; (void)out_size;

    const int tb = 256;

    // CSR build
    (void)hipMemsetAsync(hist, 0, (size_t)N * 4, stream);
    const int E4 = E / 4;
    hist_kernel<<<(E4 + tb - 1) / tb, tb, 0, stream>>>(L_row, hist, E4);
    const int nb = (N + 255) / 256;
    scan1<<<nb, 256, 0, stream>>>(hist, rs, bsums, N);
    scan2<<<1, 1024, 0, stream>>>(bsums, nb);
    scan3<<<(N + tb - 1) / tb, tb, 0, stream>>>(rs, bsums, cursor, N, E);
    scatter_kernel<<<(E4 + tb - 1) / tb, tb, 0, stream>>>(L_row, L_col, L_val, cursor,
                                                          edges, E4);

    // feats -> fp16
    const int nu8 = userNum * EMBED / 8, ni8 = itemNum * EMBED / 8;
    f32_to_f16<<<(nu8 + tb - 1) / tb, tb, 0, stream>>>(uE, h0, nu8);
    f32_to_f16<<<(ni8 + tb - 1) / tb, tb, 0, stream>>>(iE, h0 + (size_t)userNum * EMBED, ni8);

    // propagation
    const int spmm_blocks = (N + 7) / 8;        // 8 rows per 256-thread block
    spmm_kernel<<<spmm_blocks, 256, 0, stream>>>(rs, edges, h0, h1, N);
    spmm_kernel<<<spmm_blocks, 256, 0, stream>>>(rs, edges, h1, h2, N);

    const int gb = (2 * B + 7) / 8;
    gather_fused<<<gb, 256, 0, stream>>>(uE, iE, h1, h2, userIdx, itemIdx,
                                         accU, accV, B, userNum);
    spmm_sel_kernel<<<gb, 256, 0, stream>>>(rs, edges, h2, userIdx, itemIdx,
                                            accU, accV, B, userNum);

    dot_kernel<<<(B + 7) / 8, 256, 0, stream>>>(accU, accV, out, B);
}

// Round 6
// 561.799 us; speedup vs baseline: 1.2575x; 1.0681x over previous
//
#include <hip/hip_runtime.h>
#include <hip/hip_fp16.h>

#define EMBED 128
#define CHUNK 8
#define T_TILE 4096
#define NB_SH 10            // 1024 rows per bucket; NB = ceil(N/1024) <= 256

// ---------------- CSR build ----------------

__global__ void hist_kernel(const int* __restrict__ row, int* __restrict__ hist, int E4) {
    int i = blockIdx.x * blockDim.x + threadIdx.x;
    if (i < E4) {
        int4 r = ((const int4*)row)[i];
        atomicAdd(&hist[r.x], 1);
        atomicAdd(&hist[r.y], 1);
        atomicAdd(&hist[r.z], 1);
        atomicAdd(&hist[r.w], 1);
    }
}

__global__ void scan1(const int* __restrict__ hist, int* __restrict__ rs,
                      int* __restrict__ bsums, int N) {
    __shared__ int s[256];
    int i = blockIdx.x * 256 + threadIdx.x;
    int x = (i < N) ? hist[i] : 0;
    s[threadIdx.x] = x;
    __syncthreads();
    for (int off = 1; off < 256; off <<= 1) {
        int t = (threadIdx.x >= off) ? s[threadIdx.x - off] : 0;
        __syncthreads();
        s[threadIdx.x] += t;
        __syncthreads();
    }
    if (i < N) rs[i] = s[threadIdx.x] - x;
    if (threadIdx.x == 255) bsums[blockIdx.x] = s[255];
}

__global__ void scan2(int* __restrict__ bsums, int nb) {
    __shared__ int s[1024];
    __shared__ int carry;
    if (threadIdx.x == 0) carry = 0;
    __syncthreads();
    for (int base = 0; base < nb; base += 1024) {
        int i = base + threadIdx.x;
        int x = (i < nb) ? bsums[i] : 0;
        s[threadIdx.x] = x;
        __syncthreads();
        for (int off = 1; off < 1024; off <<= 1) {
            int t = (threadIdx.x >= off) ? s[threadIdx.x - off] : 0;
            __syncthreads();
            s[threadIdx.x] += t;
            __syncthreads();
        }
        if (i < nb) bsums[i] = s[threadIdx.x] - x + carry;
        __syncthreads();
        if (threadIdx.x == 0) carry += s[1023];
        __syncthreads();
    }
}

__global__ void scan3(int* __restrict__ rs, const int* __restrict__ bsums,
                      int* __restrict__ cursor, int N, int E) {
    int i = blockIdx.x * blockDim.x + threadIdx.x;
    if (i < N) {
        int v = rs[i] + bsums[i >> 8];
        rs[i] = v;
        cursor[i] = v;
    }
    if (i == 0) rs[N] = E;
}

__global__ void binit(const int* __restrict__ rs, int* __restrict__ bcursor,
                      int N, int nbuckets) {
    int b = blockIdx.x * blockDim.x + threadIdx.x;
    if (b < nbuckets) {
        int r = b << NB_SH;
        if (r > N) r = N;
        bcursor[b] = rs[r];
    }
}

// Pass A: tile-local counting sort into bucket regions (contiguous runs of writes)
__global__ __launch_bounds__(256) void passA(const int* __restrict__ row,
                                             const int* __restrict__ col,
                                             const float* __restrict__ val,
                                             int* __restrict__ bcursor,
                                             long long* __restrict__ bedges, int E) {
    __shared__ int sh_scan[256];    // inclusive scan (frozen after scan)
    __shared__ int sh_start[256];   // frozen exclusive start
    __shared__ int sh_cur[256];     // running LDS cursor
    __shared__ int sh_base[256];    // global base per bucket
    __shared__ long long sh_data[T_TILE];
    __shared__ int sh_gpos[T_TILE];
    const int t0  = blockIdx.x * T_TILE;
    const int tid = threadIdx.x;

    sh_scan[tid] = 0;
    __syncthreads();
    #pragma unroll
    for (int i = 0; i < T_TILE / 256; ++i) {
        int idx = t0 + i * 256 + tid;
        if (idx < E) atomicAdd(&sh_scan[row[idx] >> NB_SH], 1);
    }
    __syncthreads();
    int x = sh_scan[tid];
    __syncthreads();
    // Hillis-Steele inclusive scan in place
    for (int off = 1; off < 256; off <<= 1) {
        int t = (tid >= off) ? sh_scan[tid - off] : 0;
        __syncthreads();
        sh_scan[tid] += t;
        __syncthreads();
    }
    int excl = sh_scan[tid] - x;
    sh_start[tid] = excl;
    sh_cur[tid]   = excl;
    sh_base[tid]  = (x > 0) ? atomicAdd(&bcursor[tid], x) : 0;
    __syncthreads();
    #pragma unroll
    for (int i = 0; i < T_TILE / 256; ++i) {
        int idx = t0 + i * 256 + tid;
        if (idx < E) {
            int   r = row[idx];
            int   c = col[idx];
            float v = val[idx];
            int   b = r >> NB_SH;
            int   p = atomicAdd(&sh_cur[b], 1);
            unsigned lo = (unsigned)(((r & ((1 << NB_SH) - 1)) << 18) | c);
            sh_data[p] = ((long long)__float_as_int(v) << 32) | (long long)lo;
            sh_gpos[p] = sh_base[b] + (p - sh_start[b]);
        }
    }
    __syncthreads();
    int tot = sh_scan[255];
    for (int p = tid; p < tot; p += 256) {
        bedges[sh_gpos[p]] = sh_data[p];
    }
}

// Pass B: one block per bucket; resolve exact CSR slot, write final edges
__global__ __launch_bounds__(1024) void passB(const int* __restrict__ rs,
                                              const long long* __restrict__ bedges,
                                              int* __restrict__ cursor,
                                              int2* __restrict__ edges, int N) {
    int b = blockIdx.x;
    int base = b << NB_SH;
    int endRow = base + (1 << NB_SH);
    if (endRow > N) endRow = N;
    int s = rs[base], e = rs[endRow];
    for (int k = s + threadIdx.x; k < e; k += 1024) {
        long long be = bedges[k];
        unsigned lo = (unsigned)be;
        int r = base + (int)(lo >> 18);
        int c = (int)(lo & 0x3FFFF);
        int pos = atomicAdd(&cursor[r], 1);
        edges[pos] = make_int2(c, (int)(be >> 32));
    }
}

// ---------------- fp32 -> fp16 convert (8 elems/thread) ----------------

__global__ void f32_to_f16(const float* __restrict__ src, __half* __restrict__ dst, int n8) {
    int i = blockIdx.x * blockDim.x + threadIdx.x;
    if (i >= n8) return;
    float4 a = ((const float4*)src)[2 * i];
    float4 b = ((const float4*)src)[2 * i + 1];
    __half2 h0 = __floats2half2_rn(a.x, a.y);
    __half2 h1 = __floats2half2_rn(a.z, a.w);
    __half2 h2 = __floats2half2_rn(b.x, b.y);
    __half2 h3 = __floats2half2_rn(b.z, b.w);
    uint4 o;
    o.x = *(unsigned int*)&h0;
    o.y = *(unsigned int*)&h1;
    o.z = *(unsigned int*)&h2;
    o.w = *(unsigned int*)&h3;
    ((uint4*)dst)[i] = o;
}

// ---------------- SpMM: 2 rows/wave (32 lanes each), fp16 h, fp32 acc ----------------

__global__ void spmm_kernel(const int* __restrict__ rs, const int2* __restrict__ edges,
                            const __half* __restrict__ hin, __half* __restrict__ hout,
                            int N) {
    int gid  = blockIdx.x * blockDim.x + threadIdx.x;
    int wave = gid >> 6;
    int lane = threadIdx.x & 63;
    int half = lane >> 5;
    int l32  = lane & 31;
    int row  = wave * 2 + half;
    if (row >= N) return;
    int s = rs[row], e = rs[row + 1];
    float4 acc = make_float4(0.f, 0.f, 0.f, 0.f);
    for (int k = s; k < e; k += CHUNK) {
        uint2 raw[CHUNK];
        float vv[CHUNK];
        #pragma unroll
        for (int j = 0; j < CHUNK; ++j) {
            bool ok  = (k + j) < e;
            int  idx = ok ? (k + j) : s;
            int2 ed  = edges[idx];
            vv[j]    = ok ? __int_as_float(ed.y) : 0.f;
            raw[j]   = *(const uint2*)(hin + (size_t)ed.x * EMBED + 4 * l32);
        }
        #pragma unroll
        for (int j = 0; j < CHUNK; ++j) {
            float2 f0 = __half22float2(*(__half2*)&raw[j].x);
            float2 f1 = __half22float2(*(__half2*)&raw[j].y);
            acc.x += vv[j] * f0.x;
            acc.y += vv[j] * f0.y;
            acc.z += vv[j] * f1.x;
            acc.w += vv[j] * f1.y;
        }
    }
    __half2 o0 = __floats2half2_rn(acc.x, acc.y);
    __half2 o1 = __floats2half2_rn(acc.z, acc.w);
    uint2 o;
    o.x = *(unsigned int*)&o0;
    o.y = *(unsigned int*)&o1;
    *(uint2*)(hout + (size_t)row * EMBED + 4 * l32) = o;
}

// layer-3 SpMM restricted to the 2B sampled rows; accumulates fp32 into accU/accV
__global__ void spmm_sel_kernel(const int* __restrict__ rs, const int2* __restrict__ edges,
                                const __half* __restrict__ hin,
                                const int* __restrict__ uIdx, const int* __restrict__ vIdx,
                                float* __restrict__ accU, float* __restrict__ accV,
                                int B, int userNum) {
    int gid  = blockIdx.x * blockDim.x + threadIdx.x;
    int wave = gid >> 6;
    int lane = threadIdx.x & 63;
    int half = lane >> 5;
    int l32  = lane & 31;
    int b    = wave * 2 + half;
    if (b >= 2 * B) return;
    int row;
    float* dst;
    if (b < B) {
        row = uIdx[b];
        dst = accU + (size_t)b * EMBED;
    } else {
        row = userNum + vIdx[b - B];
        dst = accV + (size_t)(b - B) * EMBED;
    }
    int s = rs[row], e = rs[row + 1];
    float4 acc = make_float4(0.f, 0.f, 0.f, 0.f);
    for (int k = s; k < e; k += CHUNK) {
        uint2 raw[CHUNK];
        float vv[CHUNK];
        #pragma unroll
        for (int j = 0; j < CHUNK; ++j) {
            bool ok  = (k + j) < e;
            int  idx = ok ? (k + j) : s;
            int2 ed  = edges[idx];
            vv[j]    = ok ? __int_as_float(ed.y) : 0.f;
            raw[j]   = *(const uint2*)(hin + (size_t)ed.x * EMBED + 4 * l32);
        }
        #pragma unroll
        for (int j = 0; j < CHUNK; ++j) {
            float2 f0 = __half22float2(*(__half2*)&raw[j].x);
            float2 f1 = __half22float2(*(__half2*)&raw[j].y);
            acc.x += vv[j] * f0.x;
            acc.y += vv[j] * f0.y;
            acc.z += vv[j] * f1.x;
            acc.w += vv[j] * f1.y;
        }
    }
    float4* dp = (float4*)(dst + 4 * l32);
    float4 d = *dp;
    d.x += acc.x; d.y += acc.y; d.z += acc.z; d.w += acc.w;
    *dp = d;
}

// acc(layers 0..2) = emb(fp32) + h1(fp16) + h2(fp16) at sampled rows
__global__ void gather_fused(const float* __restrict__ uE, const float* __restrict__ iE,
                             const __half* __restrict__ h1, const __half* __restrict__ h2,
                             const int* __restrict__ uIdx, const int* __restrict__ vIdx,
                             float* __restrict__ accU, float* __restrict__ accV,
                             int B, int userNum) {
    int gid  = blockIdx.x * blockDim.x + threadIdx.x;
    int wave = gid >> 6;
    int lane = threadIdx.x & 63;
    int half = lane >> 5;
    int l32  = lane & 31;
    int b    = wave * 2 + half;
    if (b >= 2 * B) return;
    const float* emb;
    size_t ro;
    float* dst;
    if (b < B) {
        int u = uIdx[b];
        emb = uE + (size_t)u * EMBED;
        ro  = (size_t)u * EMBED;
        dst = accU + (size_t)b * EMBED;
    } else {
        int it = vIdx[b - B];
        emb = iE + (size_t)it * EMBED;
        ro  = (size_t)(userNum + it) * EMBED;
        dst = accV + (size_t)(b - B) * EMBED;
    }
    float4 a = *(const float4*)(emb + 4 * l32);
    uint2 r1 = *(const uint2*)(h1 + ro + 4 * l32);
    uint2 r2 = *(const uint2*)(h2 + ro + 4 * l32);
    float2 x0 = __half22float2(*(__half2*)&r1.x);
    float2 x1 = __half22float2(*(__half2*)&r1.y);
    float2 y0 = __half22float2(*(__half2*)&r2.x);
    float2 y1 = __half22float2(*(__half2*)&r2.y);
    a.x += x0.x + y0.x;
    a.y += x0.y + y0.y;
    a.z += x1.x + y1.x;
    a.w += x1.y + y1.y;
    *(float4*)(dst + 4 * l32) = a;
}

__global__ void dot_kernel(const float* __restrict__ accU, const float* __restrict__ accV,
                           float* __restrict__ out, int B) {
    int gid  = blockIdx.x * blockDim.x + threadIdx.x;
    int wave = gid >> 6;
    int lane = threadIdx.x & 63;
    int half = lane >> 5;
    int l32  = lane & 31;
    int b    = wave * 2 + half;
    if (b >= B) return;
    float4 a = *(const float4*)(accU + (size_t)b * EMBED + 4 * l32);
    float4 v = *(const float4*)(accV + (size_t)b * EMBED + 4 * l32);
    float s = a.x * v.x + a.y * v.y + a.z * v.z + a.w * v.w;
    #pragma unroll
    for (int off = 16; off > 0; off >>= 1) s += __shfl_down(s, off, 32);
    if (l32 == 0) out[b] = s * (1.f / 16.f);   // (acc/4)·(acc/4)
}

// ---------------- launch ----------------

extern "C" void kernel_launch(void* const* d_in, const int* in_sizes, int n_in,
                              void* d_out, int out_size, void* d_ws, size_t ws_size,
                              hipStream_t stream) {
    const float* uE      = (const float*)d_in[0];
    const float* iE      = (const float*)d_in[1];
    const float* L_val   = (const float*)d_in[2];
    const int*   L_row   = (const int*)d_in[3];
    const int*   L_col   = (const int*)d_in[4];
    const int*   userIdx = (const int*)d_in[5];
    const int*   itemIdx = (const int*)d_in[6];

    const int userNum = in_sizes[0] / EMBED;   // 100000
    const int itemNum = in_sizes[1] / EMBED;   // 50000
    const int N = userNum + itemNum;           // 150000
    const int E = in_sizes[2];                 // 2000000
    const int B = in_sizes[5];                 // 16384
    float* out = (float*)d_out;

    char* ws = (char*)d_ws;
    size_t off = 0;
    auto alloc = [&](size_t bytes) -> void* {
        void* p = ws + off;
        off += (bytes + 1023) & ~(size_t)1023;
        return p;
    };
    __half* h0     = (__half*)alloc((size_t)N * EMBED * 2);
    __half* h1     = (__half*)alloc((size_t)N * EMBED * 2);
    __half* h2     = (__half*)alloc((size_t)N * EMBED * 2);
    int2*   edges  = (int2*) alloc((size_t)E * 8);
    long long* bedges = (long long*)alloc((size_t)E * 8);
    int*    rs     = (int*)  alloc((size_t)(N + 1) * 4);
    int*    cursor = (int*)  alloc((size_t)N * 4);
    int*    hist   = (int*)  alloc((size_t)N * 4);
    int*    bsums  = (int*)  alloc(8192);
    int*    bcursor= (int*)  alloc(1024);
    float*  accU   = (float*)alloc((size_t)B * EMBED * 4);
    float*  accV   = (float*)alloc((size_t)B * EMBED * 4);
    (void)off; (void)ws_size; (void)n_in; (void)out_size;

    const int tb = 256;
    const int NBUCKETS = (N + (1 << NB_SH) - 1) >> NB_SH;   // 147 (<=256 required)

    // CSR build: hist -> scan -> bucket sort (passA) -> exact placement (passB)
    (void)hipMemsetAsync(hist, 0, (size_t)N * 4, stream);
    const int E4 = E / 4;
    hist_kernel<<<(E4 + tb - 1) / tb, tb, 0, stream>>>(L_row, hist, E4);
    const int nb = (N + 255) / 256;
    scan1<<<nb, 256, 0, stream>>>(hist, rs, bsums, N);
    scan2<<<1, 1024, 0, stream>>>(bsums, nb);
    scan3<<<(N + tb - 1) / tb, tb, 0, stream>>>(rs, bsums, cursor, N, E);
    binit<<<1, 256, 0, stream>>>(rs, bcursor, N, NBUCKETS);
    passA<<<(E + T_TILE - 1) / T_TILE, 256, 0, stream>>>(L_row, L_col, L_val,
                                                         bcursor, bedges, E);
    passB<<<NBUCKETS, 1024, 0, stream>>>(rs, bedges, cursor, edges, N);

    // feats -> fp16
    const int nu8 = userNum * EMBED / 8, ni8 = itemNum * EMBED / 8;
    f32_to_f16<<<(nu8 + tb - 1) / tb, tb, 0, stream>>>(uE, h0, nu8);
    f32_to_f16<<<(ni8 + tb - 1) / tb, tb, 0, stream>>>(iE, h0 + (size_t)userNum * EMBED, ni8);

    // propagation
    const int spmm_blocks = (N + 7) / 8;        // 8 rows per 256-thread block
    spmm_kernel<<<spmm_blocks, 256, 0, stream>>>(rs, edges, h0, h1, N);
    spmm_kernel<<<spmm_blocks, 256, 0, stream>>>(rs, edges, h1, h2, N);

    const int gb = (2 * B + 7) / 8;
    gather_fused<<<gb, 256, 0, stream>>>(uE, iE, h1, h2, userIdx, itemIdx,
                                         accU, accV, B, userNum);
    spmm_sel_kernel<<<gb, 256, 0, stream>>>(rs, edges, h2, userIdx, itemIdx,
                                            accU, accV, B, userNum);

    dot_kernel<<<(B + 7) / 8, 256, 0, stream>>>(accU, accV, out, B);
}